// Round 1
// baseline (68.133 us; speedup 1.0000x reference)
//
#include <hip/hip_runtime.h>
#include <hip/hip_bf16.h>
#include <math.h>

// Inverse Radon backprojection.
// sinogram: (B, N=180, W=512) fp32;  angles: (N,) degrees fp32
// output:   (B, 1, H=512, W=512) fp32
//
// Per output pixel (y,x):
//   xs = -1 + x*2/(W-1), ys = -1 + y*2/(W-1)
//   for each angle: rotate, bilinear-tap the sinogram row n at detector coord
//   ix, weighted by the y-boundary weight yw; accumulate; divide by N.

#define IRD_W 512
#define IRD_N 180

__global__ __launch_bounds__(256) void iradon_kernel(
    const float* __restrict__ sino,    // B*N*W
    const float* __restrict__ angles,  // N
    float* __restrict__ out,           // B*H*W
    int total)                         // B*H*W
{
    __shared__ float s_cos[IRD_N];
    __shared__ float s_sin[IRD_N];

    const int tid = threadIdx.x;
    for (int n = tid; n < IRD_N; n += blockDim.x) {
        float th = angles[n] * 0.017453292519943295f;  // deg2rad
        float sv, cv;
        sincosf(th, &sv, &cv);
        s_cos[n] = cv;
        s_sin[n] = sv;
    }
    __syncthreads();

    const int pix = blockIdx.x * blockDim.x + tid;
    if (pix >= total) return;

    const int W = IRD_W;
    const int x = pix & (W - 1);
    const int yy = pix >> 9;          // W==512
    const int y = yy & (W - 1);       // row within image
    const int b = pix >> 18;          // batch (H*W == 2^18)

    const float step = 2.0f / (float)(W - 1);
    const float xs = -1.0f + (float)x * step;
    const float ys = -1.0f + (float)y * step;
    const float half = 0.5f * (float)(W - 1);
    const float wmax = (float)(W - 1);

    const float* __restrict__ sb = sino + (size_t)b * IRD_N * W;

    float acc = 0.0f;

    #pragma unroll 4
    for (int n = 0; n < IRD_N; ++n) {
        const float c = s_cos[n];
        const float s = s_sin[n];

        const float gx = c * xs + s * ys;
        const float gy = c * ys - s * xs;

        const float ix = (gx + 1.0f) * half;
        const float iy = (gy + 1.0f) * half;

        // x taps
        const float x0f = floorf(ix);
        const float wx1 = ix - x0f;
        const float wx0 = 1.0f - wx1;
        const float x1f = x0f + 1.0f;
        const float mx0 = (x0f >= 0.0f && x0f <= wmax) ? 1.0f : 0.0f;
        const float mx1 = (x1f >= 0.0f && x1f <= wmax) ? 1.0f : 0.0f;
        int x0i = (int)fminf(fmaxf(x0f, 0.0f), wmax);
        int x1i = (int)fminf(fmaxf(x1f, 0.0f), wmax);

        // y boundary weight (no y-indexing into sinogram in the reference)
        const float y0f = floorf(iy);
        const float wy1 = iy - y0f;
        const float wy0 = 1.0f - wy1;
        const float y1f = y0f + 1.0f;
        const float my0 = (y0f >= 0.0f && y0f <= wmax) ? 1.0f : 0.0f;
        const float my1 = (y1f >= 0.0f && y1f <= wmax) ? 1.0f : 0.0f;
        const float yw = wy0 * my0 + wy1 * my1;

        const float* __restrict__ row = sb + n * W;
        const float g0 = row[x0i];
        const float g1 = row[x1i];

        acc += (wx0 * mx0 * g0 + wx1 * mx1 * g1) * yw;
    }

    out[pix] = acc * (1.0f / (float)IRD_N);
}

extern "C" void kernel_launch(void* const* d_in, const int* in_sizes, int n_in,
                              void* d_out, int out_size, void* d_ws, size_t ws_size,
                              hipStream_t stream) {
    const float* sino = (const float*)d_in[0];
    const float* angles = (const float*)d_in[1];
    float* out = (float*)d_out;

    const int total = out_size;  // B*1*H*W
    const int block = 256;
    const int grid = (total + block - 1) / block;

    iradon_kernel<<<grid, block, 0, stream>>>(sino, angles, out, total);
}

// Round 2
// 35.378 us; speedup vs baseline: 1.9258x; 1.9258x over previous
//
#include <hip/hip_runtime.h>
#include <hip/hip_bf16.h>
#include <math.h>

// Inverse Radon backprojection, VALU-minimized.
// sinogram: (B=1, N=180, W=512) fp32;  angles: (N,) degrees fp32
// output:   (B, 1, 512, 512) fp32
//
// Key identities vs reference:
//  - zero-padded sinogram rows (width 768, data at [128,640)) make
//    wx0*mx0*g0 + wx1*mx1*g1 == wx0*pad[x0] + wx1*pad[x0+1] exactly
//    (out-of-range taps read 0.0; masks and clamps eliminated).
//  - yw = wy0*my0 + wy1*my1 == sat(iy+1) * sat(512-iy)  (med3 clamp),
//    eliminating floor(iy) and both y masks.

#define IRD_W 512
#define IRD_N 180
#define PADW 768
#define POFF 128

__global__ __launch_bounds__(256) void iradon_prep_kernel(
    const float* __restrict__ sino,   // B*N*W
    float* __restrict__ pad,          // B*N*PADW
    int total)                        // B*N*PADW
{
    int i = blockIdx.x * blockDim.x + threadIdx.x;
    if (i >= total) return;
    int j = i % PADW;
    int row = i / PADW;               // b*N + n
    float v = 0.0f;
    int src = j - POFF;
    if (src >= 0 && src < IRD_W) v = sino[row * IRD_W + src];
    pad[i] = v;
}

__global__ __launch_bounds__(256) void iradon_pad_kernel(
    const float* __restrict__ pad,     // B*N*PADW, zero-padded
    const float* __restrict__ angles,  // N
    float* __restrict__ out,           // B*H*W
    int total)
{
    __shared__ float2 s_trig[IRD_N];   // {c*half, s*half}

    const int tid = threadIdx.x;
    const float half = 0.5f * (float)(IRD_W - 1);  // 255.5
    for (int n = tid; n < IRD_N; n += blockDim.x) {
        float th = angles[n] * 0.017453292519943295f;
        float sv, cv;
        sincosf(th, &sv, &cv);
        s_trig[n] = make_float2(cv * half, sv * half);
    }
    __syncthreads();

    const int pix = blockIdx.x * blockDim.x + tid;
    if (pix >= total) return;

    const int W = IRD_W;
    const int x = pix & (W - 1);
    const int y = (pix >> 9) & (W - 1);
    const int b = pix >> 18;

    const float step = 2.0f / (float)(W - 1);
    const float xs = -1.0f + (float)x * step;
    const float ys = -1.0f + (float)y * step;

    const float* __restrict__ rowb = pad + (size_t)b * IRD_N * PADW + POFF;

    float acc = 0.0f;

    #pragma unroll 4
    for (int n = 0; n < IRD_N; ++n) {
        const float2 t = s_trig[n];
        const float ch = t.x, sh = t.y;

        // ix = (gx+1)*half = ch*xs + sh*ys + half ; iy likewise
        const float ix = ch * xs + (sh * ys + half);
        const float iy = ch * ys - (sh * xs - half);

        const float x0f = floorf(ix);
        const float w1 = ix - x0f;
        const float w0 = 1.0f - w1;
        const int x0 = (int)x0f;           // in [-106, 617] -> padded idx ok

        const float* __restrict__ r = rowb + n * PADW + x0;
        const float g0 = r[0];
        const float g1 = r[1];

        const float a  = __builtin_amdgcn_fmed3f(iy + 1.0f, 0.0f, 1.0f);
        const float bb = __builtin_amdgcn_fmed3f(512.0f - iy, 0.0f, 1.0f);
        const float yw = a * bb;

        acc += (w0 * g0 + w1 * g1) * yw;
    }

    out[pix] = acc * (1.0f / (float)IRD_N);
}

// Fallback (no workspace): fully masked version, known-correct from round 1.
__global__ __launch_bounds__(256) void iradon_kernel(
    const float* __restrict__ sino,
    const float* __restrict__ angles,
    float* __restrict__ out,
    int total)
{
    __shared__ float s_cos[IRD_N];
    __shared__ float s_sin[IRD_N];

    const int tid = threadIdx.x;
    for (int n = tid; n < IRD_N; n += blockDim.x) {
        float th = angles[n] * 0.017453292519943295f;
        float sv, cv;
        sincosf(th, &sv, &cv);
        s_cos[n] = cv;
        s_sin[n] = sv;
    }
    __syncthreads();

    const int pix = blockIdx.x * blockDim.x + tid;
    if (pix >= total) return;

    const int W = IRD_W;
    const int x = pix & (W - 1);
    const int y = (pix >> 9) & (W - 1);
    const int b = pix >> 18;

    const float step = 2.0f / (float)(W - 1);
    const float xs = -1.0f + (float)x * step;
    const float ys = -1.0f + (float)y * step;
    const float half = 0.5f * (float)(W - 1);
    const float wmax = (float)(W - 1);

    const float* __restrict__ sb = sino + (size_t)b * IRD_N * W;

    float acc = 0.0f;
    for (int n = 0; n < IRD_N; ++n) {
        const float c = s_cos[n];
        const float s = s_sin[n];
        const float gx = c * xs + s * ys;
        const float gy = c * ys - s * xs;
        const float ix = (gx + 1.0f) * half;
        const float iy = (gy + 1.0f) * half;
        const float x0f = floorf(ix);
        const float wx1 = ix - x0f;
        const float wx0 = 1.0f - wx1;
        const float x1f = x0f + 1.0f;
        const float mx0 = (x0f >= 0.0f && x0f <= wmax) ? 1.0f : 0.0f;
        const float mx1 = (x1f >= 0.0f && x1f <= wmax) ? 1.0f : 0.0f;
        int x0i = (int)fminf(fmaxf(x0f, 0.0f), wmax);
        int x1i = (int)fminf(fmaxf(x1f, 0.0f), wmax);
        const float y0f = floorf(iy);
        const float wy1 = iy - y0f;
        const float wy0 = 1.0f - wy1;
        const float y1f = y0f + 1.0f;
        const float my0 = (y0f >= 0.0f && y0f <= wmax) ? 1.0f : 0.0f;
        const float my1 = (y1f >= 0.0f && y1f <= wmax) ? 1.0f : 0.0f;
        const float yw = wy0 * my0 + wy1 * my1;
        const float* __restrict__ row = sb + n * W;
        acc += (wx0 * mx0 * row[x0i] + wx1 * mx1 * row[x1i]) * yw;
    }
    out[pix] = acc * (1.0f / (float)IRD_N);
}

extern "C" void kernel_launch(void* const* d_in, const int* in_sizes, int n_in,
                              void* d_out, int out_size, void* d_ws, size_t ws_size,
                              hipStream_t stream) {
    const float* sino = (const float*)d_in[0];
    const float* angles = (const float*)d_in[1];
    float* out = (float*)d_out;

    const int total = out_size;                    // B*1*H*W
    const int B = total >> 18;                     // H*W == 2^18
    const size_t pad_elems = (size_t)B * IRD_N * PADW;
    const size_t pad_bytes = pad_elems * sizeof(float);

    const int block = 256;
    const int grid = (total + block - 1) / block;

    if (ws_size >= pad_bytes) {
        float* pad = (float*)d_ws;
        const int ptotal = (int)pad_elems;
        iradon_prep_kernel<<<(ptotal + block - 1) / block, block, 0, stream>>>(
            sino, pad, ptotal);
        iradon_pad_kernel<<<grid, block, 0, stream>>>(pad, angles, out, total);
    } else {
        iradon_kernel<<<grid, block, 0, stream>>>(sino, angles, out, total);
    }
}